// Round 6
// baseline (336.363 us; speedup 1.0000x reference)
//
#include <hip/hip_runtime.h>
#include <math.h>

#define NHID  1024
#define NCLS  224
#define NTPC  225
#define BATCH 2048

#define KSPLIT 8                     // K-chunks of 128 rows
#define KCH    128
#define NTILES (BATCH / 16)          // 128 sample-tiles for the top GEMM
#define NBOT_BLOCKS (NCLS * KSPLIT)      // 1792
#define NTOP_BLOCKS (NTILES * KSPLIT)    // 1024

#define YTS 224                      // top slab row stride (== NCLS, 16B-mult)
#define YBS 228                      // bottom slab row stride (padded, 16B-mult)
#define YTOPK (BATCH * YTS)          // floats per top k-slab
#define YBOTK (BATCH * YBS)          // floats per bottom k-slab

// ws layout (bytes):
#define CLS_OFF  0
#define POS_OFF  8192
#define LIST_OFF 16384
#define OFFS_OFF 24576
#define YTOP_OFF 32768
#define YTOP_BYTES (KSPLIT * YTOPK * 4)
#define YBOT_OFF (YTOP_OFF + YTOP_BYTES)
#define YBOT_BYTES (KSPLIT * YBOTK * 4)

// ---------------------------------------------------------------------------
// Pass 0: label decode (int32/int64 autodetect), class/pos, group-by-class.
// ---------------------------------------------------------------------------
__global__ __launch_bounds__(256) void group_kernel(const int* __restrict__ labels,
                                                    int* __restrict__ cls,
                                                    int* __restrict__ pos,
                                                    int* __restrict__ list,
                                                    int* __restrict__ offs) {
    __shared__ int cnt[NCLS];
    __shared__ int sc[256];
    __shared__ int bex[NCLS];
    __shared__ int nz;
    const int tid = threadIdx.x;
    if (tid == 0) nz = 0;
    for (int j = tid; j < NCLS; j += 256) cnt[j] = 0;
    __syncthreads();
    int loc = 0;
    for (int k = 0; k < 4; ++k) {
        int i = tid + 256 * k;
        if (labels[2 * i + 1] != 0) loc = 1;
    }
    if (loc) atomicOr(&nz, 1);
    __syncthreads();
    const bool is64 = (nz == 0);
    int myc[8], myr[8];
#pragma unroll
    for (int k = 0; k < 8; ++k) {
        int i = tid + 256 * k;
        int l = is64 ? labels[2 * i] : labels[i];
        int c = l / NTPC;
        cls[i] = c;
        pos[i] = l - c * NTPC;
        myc[k] = c;
        myr[k] = atomicAdd(&cnt[c], 1);
    }
    __syncthreads();
    int v = (tid < NCLS) ? cnt[tid] : 0;
    sc[tid] = v;
    __syncthreads();
    for (int off = 1; off < 256; off <<= 1) {
        int u = (tid >= off) ? sc[tid - off] : 0;
        __syncthreads();
        sc[tid] += u;
        __syncthreads();
    }
    if (tid < NCLS) {
        int ex = sc[tid] - v;
        bex[tid] = ex;
        offs[tid] = ex;
    }
    if (tid == 0) offs[NCLS] = BATCH;
    __syncthreads();
#pragma unroll
    for (int k = 0; k < 8; ++k) {
        int i = tid + 256 * k;
        list[bex[myc[k]] + myr[k]] = i;
    }
}

// ---------------------------------------------------------------------------
// Pass 1: K-split partial GEMMs, chunk = 128 rows, KSPLIT = 8, 2816 blocks.
// Round 0-4 invariant: all inner-loop variants land at 113-135us with
// VALUBusy 17-21% (~80% latency stall). Confirmed failure modes: compiler
// pins VGPR=32 and serializes the W stream (r1, r3); aligned(4) f4u quad
// loads on bottom's 900B-stride rows are not guaranteed dwordx4 (r4).
// This round, path-specialized W access with explicit 2-deep ping-pong
// register prefetch (compile-time indices only) under a 128-VGPR budget:
//  - TOP  (stride 896B, 16B-aligned): lane l owns cols 4l..4l+3, true
//    float4 loads, wva[4]/wvb[4].
//  - BOT  (stride 900B): lane l owns cols {l, l+64, l+128, 192+l}; scalar
//    dword loads (always aligned, 256B-coalesced per group),
//    wva[16]/wvb[16] -> 16 loads structurally in flight.
// Per row per wave: 1 broadcast ds_read_b128 (own sample quad) + W loads
// + 16 FMAs. Wave w owns samples 4w..4w+3.
// Outputs: plain stores into per-k slabs; finalize sums slabs.
// Block-index transpose (c = bi % 224, 224 % 8 == 0): chunks of one target
// on the same XCD for L2 locality of x and y.
// ---------------------------------------------------------------------------
template<int YC, int YS, bool BOT>
__device__ __forceinline__ void run_tiles(const float* __restrict__ x,
                                          const float* __restrict__ W,
                                          float* __restrict__ yk,
                                          const int* __restrict__ list,
                                          int o, int n, int hbase,
                                          float* __restrict__ xs) {
    const int tid = threadIdx.x;
    const int w = tid >> 6, l = tid & 63;
    const int r  = tid & 127;                   // staging row within chunk
    const int hs = tid >> 7;                    // sample-half (0: i<8, 1: i>=8)
    const int rq = (r >> 1) & 3;                // staging swizzle key
    const float4* xsq = (const float4*)xs;

    for (int tile = 0; tile * 16 < n; ++tile) {
        if (tile) __syncthreads();              // xs reuse vs prior compute reads
        // stage: rows r=tid&127, each thread stages 8 samples of its row.
        // Split: 8 independent index loads, then 8 independent x loads
        // (shortens the gather critical path). For fixed j a wave's 64
        // lanes cover 64 consecutive rows -> 256B coalesced x loads.
        int sidx[8];
#pragma unroll
        for (int j = 0; j < 8; ++j) {
            const int idx = tile * 16 + hs * 8 + j;
            sidx[j] = BOT ? list[o + min(idx, n - 1)] : (o + min(idx, n - 1));
        }
        const float* xrow = x + hbase + r;
#pragma unroll
        for (int j = 0; j < 8; ++j) {
            const int i = hs * 8 + j;
            xs[(r << 4) + ((((i >> 2) ^ rq) << 2) | (i & 3))] =
                xrow[(size_t)sidx[j] * NHID];
        }
        __syncthreads();

        float acc[16];                          // [sample-in-quad][colgroup]
#pragma unroll
        for (int i = 0; i < 16; ++i) acc[i] = 0.f;

        if (BOT) {
            // ---- bottom: scalar dword W loads, 4-row groups, 2-deep ----
            const float* wp = W + (size_t)hbase * YC + l;
            const float* w3 = W + (size_t)hbase * YC + min(192 + l, YC - 1);

            float wva[16], wvb[16];
#define LOADB(dst, p0, p3)                                                  \
            _Pragma("unroll")                                               \
            for (int j = 0; j < 4; ++j) {                                   \
                dst[4 * j + 0] = (p0)[(size_t)j * YC];                      \
                dst[4 * j + 1] = (p0)[(size_t)j * YC + 64];                 \
                dst[4 * j + 2] = (p0)[(size_t)j * YC + 128];                \
                dst[4 * j + 3] = (p3)[(size_t)j * YC];                      \
            }
#define COMPB(hb, ph, v)                                                    \
            _Pragma("unroll")                                               \
            for (int j = 0; j < 4; ++j) {                                   \
                const float4 xv = xsq[((hb) + j) * 4 + (w ^ ((ph) + (j >> 1)))]; \
                acc[0]  = fmaf(xv.x, v[4 * j + 0], acc[0]);                 \
                acc[1]  = fmaf(xv.x, v[4 * j + 1], acc[1]);                 \
                acc[2]  = fmaf(xv.x, v[4 * j + 2], acc[2]);                 \
                acc[3]  = fmaf(xv.x, v[4 * j + 3], acc[3]);                 \
                acc[4]  = fmaf(xv.y, v[4 * j + 0], acc[4]);                 \
                acc[5]  = fmaf(xv.y, v[4 * j + 1], acc[5]);                 \
                acc[6]  = fmaf(xv.y, v[4 * j + 2], acc[6]);                 \
                acc[7]  = fmaf(xv.y, v[4 * j + 3], acc[7]);                 \
                acc[8]  = fmaf(xv.z, v[4 * j + 0], acc[8]);                 \
                acc[9]  = fmaf(xv.z, v[4 * j + 1], acc[9]);                 \
                acc[10] = fmaf(xv.z, v[4 * j + 2], acc[10]);                \
                acc[11] = fmaf(xv.z, v[4 * j + 3], acc[11]);                \
                acc[12] = fmaf(xv.w, v[4 * j + 0], acc[12]);                \
                acc[13] = fmaf(xv.w, v[4 * j + 1], acc[13]);                \
                acc[14] = fmaf(xv.w, v[4 * j + 2], acc[14]);                \
                acc[15] = fmaf(xv.w, v[4 * j + 3], acc[15]);                \
            }
            LOADB(wva, wp, w3)
#pragma unroll 1
            for (int h0 = 0; h0 < KCH; h0 += 8) {
                LOADB(wvb, wp + 4 * (size_t)YC, w3 + 4 * (size_t)YC)
                COMPB(h0, 0, wva)
                const int adv = (h0 + 8 < KCH) ? 8 : 0;   // dead-final clamp
                LOADB(wva, wp + adv * (size_t)YC, w3 + adv * (size_t)YC)
                COMPB(h0 + 4, 2, wvb)
                wp += 8 * (size_t)YC;
                w3 += 8 * (size_t)YC;
            }
#undef LOADB
#undef COMPB
            // epilogue: 4 coalesced 256B store groups per sample
            const int nt = min(n - tile * 16, 16);
#pragma unroll
            for (int jj = 0; jj < 4; ++jj) {
                const int it = 4 * w + jj;
                if (it < nt) {
                    const int s = list[o + tile * 16 + it];
                    float* yr = yk + (size_t)s * YS;
                    yr[l]       = acc[4 * jj + 0];
                    yr[l + 64]  = acc[4 * jj + 1];
                    yr[l + 128] = acc[4 * jj + 2];
                    if (l + 192 < YC) yr[l + 192] = acc[4 * jj + 3];
                }
            }
        } else {
            // ---- top: 16B-aligned float4 W loads, 4-row groups, 2-deep ----
            const int cb = 4 * l;
            const int cbc = min(cb, YC - 4);
            const float* wp = W + (size_t)hbase * YC + cbc;
            float4 wva[4], wvb[4];
#define LOADT(dst, p)                                                       \
            _Pragma("unroll")                                               \
            for (int j = 0; j < 4; ++j)                                     \
                dst[j] = *(const float4*)((p) + (size_t)j * YC);
#define COMPT(hb, ph, v)                                                    \
            _Pragma("unroll")                                               \
            for (int j = 0; j < 4; ++j) {                                   \
                const float4 xv = xsq[((hb) + j) * 4 + (w ^ ((ph) + (j >> 1)))]; \
                const float4 wq = v[j];                                     \
                acc[0]  = fmaf(xv.x, wq.x, acc[0]);                         \
                acc[1]  = fmaf(xv.x, wq.y, acc[1]);                         \
                acc[2]  = fmaf(xv.x, wq.z, acc[2]);                         \
                acc[3]  = fmaf(xv.x, wq.w, acc[3]);                         \
                acc[4]  = fmaf(xv.y, wq.x, acc[4]);                         \
                acc[5]  = fmaf(xv.y, wq.y, acc[5]);                         \
                acc[6]  = fmaf(xv.y, wq.z, acc[6]);                         \
                acc[7]  = fmaf(xv.y, wq.w, acc[7]);                         \
                acc[8]  = fmaf(xv.z, wq.x, acc[8]);                         \
                acc[9]  = fmaf(xv.z, wq.y, acc[9]);                         \
                acc[10] = fmaf(xv.z, wq.z, acc[10]);                        \
                acc[11] = fmaf(xv.z, wq.w, acc[11]);                        \
                acc[12] = fmaf(xv.w, wq.x, acc[12]);                        \
                acc[13] = fmaf(xv.w, wq.y, acc[13]);                        \
                acc[14] = fmaf(xv.w, wq.z, acc[14]);                        \
                acc[15] = fmaf(xv.w, wq.w, acc[15]);                        \
            }
            LOADT(wva, wp)
#pragma unroll 1
            for (int h0 = 0; h0 < KCH; h0 += 8) {
                LOADT(wvb, wp + 4 * (size_t)YC)
                COMPT(h0, 0, wva)
                const int adv = (h0 + 8 < KCH) ? 8 : 0;   // dead-final clamp
                LOADT(wva, wp + adv * (size_t)YC)
                COMPT(h0 + 4, 2, wvb)
                wp += 8 * (size_t)YC;
            }
#undef LOADT
#undef COMPT
            // epilogue: 16B-aligned quad store (YS*4 % 16 == 0)
            const int nt = min(n - tile * 16, 16);
#pragma unroll
            for (int jj = 0; jj < 4; ++jj) {
                const int it = 4 * w + jj;
                if (it < nt && cb + 3 < YC) {
                    const int s = o + tile * 16 + it;
                    float* yr = yk + (size_t)s * YS;
                    *(float4*)(yr + cb) =
                        make_float4(acc[4 * jj + 0], acc[4 * jj + 1],
                                    acc[4 * jj + 2], acc[4 * jj + 3]);
                }
            }
        }
    }
}

__global__ __launch_bounds__(256, 4) void partial_kernel(const float* __restrict__ x,
                                                         const float* __restrict__ Wt,
                                                         const float* __restrict__ Wb,
                                                         const int* __restrict__ list,
                                                         const int* __restrict__ offs,
                                                         float* __restrict__ ytop,
                                                         float* __restrict__ ybot) {
    __shared__ __align__(16) float xs[KCH * 16];   // 8 KB
    const int bi = blockIdx.x;
    if (bi < NBOT_BLOCKS) {
        const int c = bi % NCLS;        // 224 % 8 == 0 -> all chunks of class c
        const int k = bi / NCLS;        // land on XCD (c % 8)
        const int o = offs[c];
        const int n = offs[c + 1] - o;
        run_tiles<NTPC, YBS, true>(x, Wb + (size_t)c * (NHID * NTPC),
                                   ybot + (size_t)k * YBOTK, list, o, n, k * KCH, xs);
    } else {
        const int b2 = bi - NBOT_BLOCKS;
        const int st = b2 % NTILES;     // 128 % 8 == 0 -> chunks of tile st
        const int k  = b2 / NTILES;     // land on one XCD
        run_tiles<NCLS, YTS, false>(x, Wt, ytop + (size_t)k * YTOPK, list,
                                    st * 16, 16, k * KCH, xs);
    }
}

// ---------------------------------------------------------------------------
// Pass 2: per-sample k-slab reduction + dual softmax + product. One wave per
// sample. Bottom slabs have padded row stride YBS.
// ---------------------------------------------------------------------------
__global__ __launch_bounds__(256) void finalize_kernel(const float* __restrict__ ytop,
                                                       const float* __restrict__ ybot,
                                                       const float* __restrict__ bt,
                                                       const float* __restrict__ bb,
                                                       const int* __restrict__ cls,
                                                       const int* __restrict__ pos,
                                                       float* __restrict__ out) {
    const int w = threadIdx.x >> 6, l = threadIdx.x & 63;
    const int s = blockIdx.x * 4 + w;
    const int c = cls[s], p = pos[s];

    float v[4];
#pragma unroll
    for (int g = 0; g < 4; ++g) {
        int col = l + 64 * g;
        if (col < NCLS) {
            float a = bt[col];
#pragma unroll
            for (int k = 0; k < KSPLIT; ++k)
                a += ytop[(size_t)k * YTOPK + (size_t)s * YTS + col];
            v[g] = a;
        } else {
            v[g] = -INFINITY;
        }
    }
    float mx = fmaxf(fmaxf(v[0], v[1]), fmaxf(v[2], v[3]));
#pragma unroll
    for (int off = 32; off; off >>= 1) mx = fmaxf(mx, __shfl_xor(mx, off));
    float sum = 0.f, tc = 0.f;
#pragma unroll
    for (int g = 0; g < 4; ++g) {
        int col = l + 64 * g;
        float e = (col < NCLS) ? __expf(v[g] - mx) : 0.f;
        sum += e;
        if (col == c) tc = e;
    }
#pragma unroll
    for (int off = 32; off; off >>= 1) {
        sum += __shfl_xor(sum, off);
        tc  += __shfl_xor(tc, off);
    }
    const float tp = tc / sum;

#pragma unroll
    for (int g = 0; g < 4; ++g) {
        int col = l + 64 * g;
        if (col < NTPC) {
            float a = bb[c * NTPC + col];
#pragma unroll
            for (int k = 0; k < KSPLIT; ++k)
                a += ybot[(size_t)k * YBOTK + (size_t)s * YBS + col];
            v[g] = a;
        } else {
            v[g] = -INFINITY;
        }
    }
    mx = fmaxf(fmaxf(v[0], v[1]), fmaxf(v[2], v[3]));
#pragma unroll
    for (int off = 32; off; off >>= 1) mx = fmaxf(mx, __shfl_xor(mx, off));
    float bsum = 0.f, ep = 0.f;
#pragma unroll
    for (int g = 0; g < 4; ++g) {
        int col = l + 64 * g;
        float e = (col < NTPC) ? __expf(v[g] - mx) : 0.f;
        bsum += e;
        if (col == p) ep = e;
    }
#pragma unroll
    for (int off = 32; off; off >>= 1) bsum += __shfl_xor(bsum, off);
#pragma unroll
    for (int g = 0; g < 4; ++g)
        if (l + 64 * g == p) out[s] = tp * ep / bsum;
}

extern "C" void kernel_launch(void* const* d_in, const int* in_sizes, int n_in,
                              void* d_out, int out_size, void* d_ws, size_t ws_size,
                              hipStream_t stream) {
    const float* inputs = (const float*)d_in[0];
    const int*   labels = (const int*)d_in[1];
    const float* topW   = (const float*)d_in[2];
    const float* topB   = (const float*)d_in[3];
    const float* botW   = (const float*)d_in[4];
    const float* botB   = (const float*)d_in[5];
    float* out = (float*)d_out;

    char* ws   = (char*)d_ws;
    int*   cls = (int*)(ws + CLS_OFF);
    int*   pos = (int*)(ws + POS_OFF);
    int*   lst = (int*)(ws + LIST_OFF);
    int*   off = (int*)(ws + OFFS_OFF);
    float* ytop = (float*)(ws + YTOP_OFF);
    float* ybot = (float*)(ws + YBOT_OFF);

    // no memset: every slab entry read by finalize is overwritten by pass 1
    group_kernel<<<1, 256, 0, stream>>>(labels, cls, pos, lst, off);
    partial_kernel<<<NBOT_BLOCKS + NTOP_BLOCKS, 256, 0, stream>>>(
        inputs, topW, botW, lst, off, ytop, ybot);
    finalize_kernel<<<BATCH / 4, 256, 0, stream>>>(ytop, ybot, topB, botB, cls, pos, out);
}